// Round 3
// baseline (685.830 us; speedup 1.0000x reference)
//
#include <hip/hip_runtime.h>
#include <math.h>

typedef __bf16 bf16_t;
typedef __attribute__((ext_vector_type(8))) __bf16 bf16x8;
typedef __attribute__((ext_vector_type(4))) __bf16 bf16x4;
typedef __attribute__((ext_vector_type(4))) float f32x4;

#define NTOK 4096   // B*L tokens
#define DDIM 1024
#define FDIM 4096
#define NEXP 8
#define CAP  4096   // per-expert token capacity (worst case)
#define HROWS (2*NTOK + 128)  // pair count + slack for gemm2 A-tile overreads
#define NPAIR (2*NTOK)
#define MAXB 72     // max live m-blocks: floor(8192/128)+7 = 71

#define PREP_BLOCKS 2048   // 8 blocks/CU: whole grid co-resident, zero churn
#define PREP_UNITS 13312   // [0,4096) W1-T | [4096,8192) W2-T | [8192,12288) x->bf16 | [12288,13312) router

// async 16B global->LDS. LDS dest must be wave-uniform base + lane*16.
#define GLOAD_LDS16(g, l) \
  __builtin_amdgcn_global_load_lds((__attribute__((address_space(1))) void*)(g), \
                                   (__attribute__((address_space(3))) void*)(l), 16, 0, 0)

__device__ __forceinline__ float fast_gelu(float v) {
  float u = 0.7978845608028654f * (v + 0.044715f * v * v * v);
  float uc = fminf(fmaxf(u, -10.f), 10.f);
  float t = __builtin_amdgcn_exp2f(2.885390081777927f * uc);  // e^{2u}
  float th = (t - 1.f) * __builtin_amdgcn_rcpf(t + 1.f);
  return 0.5f * v * (1.0f + th);
}

// ---------------------------------------------------------------- prep
// Persistent grid-stride kernel. 2048 blocks loop over 13312 units so the next
// unit's load burst issues right after the current unit's stores — continuous
// VMEM occupancy (one-shot blocks measured latency-bound at 1.44 TB/s).
__device__ __forceinline__ void reg_transpose(const float* __restrict__ ip,
                                              bf16_t* __restrict__ op,
                                              int R, int C, int r0, int c0,
                                              int t) {
  const int w = t >> 6;
  const int lane = t & 63;
  const int g = lane >> 4;
  const int m = lane & 15;
  const int rr = r0 + w * 32 + 8 * g;   // 8 input rows [rr, rr+8)
  const int cc = c0 + 4 * m;            // 4 input cols [cc, cc+4)
  f32x4 v[8];
#pragma unroll
  for (int ri = 0; ri < 8; ri++)
    v[ri] = *(const f32x4*)(ip + (size_t)(rr + ri) * C + cc);
#pragma unroll
  for (int ci = 0; ci < 4; ci++) {
    bf16x8 o;
#pragma unroll
    for (int ri = 0; ri < 8; ri++) o[ri] = (bf16_t)v[ri][ci];
    *(bf16x8*)(op + (size_t)(cc + ci) * R + rr) = o;
  }
}

__global__ __launch_bounds__(256) void prep_kernel(
    const float* __restrict__ W1, const float* __restrict__ W2,
    const float* __restrict__ x, const float* __restrict__ Wg,
    bf16_t* __restrict__ wt1, bf16_t* __restrict__ wt2,
    bf16_t* __restrict__ xbf, int* __restrict__ tokL, int* __restrict__ cnts,
    int* __restrict__ pairE, int* __restrict__ pairS, float* __restrict__ pairG) {
  const int t = threadIdx.x;
  for (int u = blockIdx.x; u < PREP_UNITS; u += PREP_BLOCKS) {
    if (u < 4096) {  // W1 (E,1024,4096) -> wt1 (E,4096,1024)
      int e = u >> 9, ti = u & 511;
      int r0 = (ti & 7) * 128, c0 = (ti >> 3) * 64;
      reg_transpose(W1 + (size_t)e * DDIM * FDIM, wt1 + (size_t)e * DDIM * FDIM,
                    DDIM, FDIM, r0, c0, t);
    } else if (u < 8192) {  // W2 (E,4096,1024) -> wt2 (E,1024,4096)
      int b0 = u - 4096;
      int e = b0 >> 9, ti = b0 & 511;
      int r0 = (ti & 31) * 128, c0 = (ti >> 5) * 64;
      reg_transpose(W2 + (size_t)e * FDIM * DDIM, wt2 + (size_t)e * FDIM * DDIM,
                    FDIM, DDIM, r0, c0, t);
    } else if (u < 12288) {  // x -> bf16 (exactly covers NTOK*DDIM/4 elements)
      int i = (u - 8192) * 256 + t;
      float4 v = ((const float4*)x)[i];
      bf16x4 o;
      o.x = (bf16_t)v.x; o.y = (bf16_t)v.y; o.z = (bf16_t)v.z; o.w = (bf16_t)v.w;
      ((bf16x4*)xbf)[i] = o;
    } else {  // router: 4 tokens/unit, one wave/token, fp64 logits
      int b0 = u - 12288;
      int wid = t >> 6, lane = t & 63;
      int n = b0 * 4 + wid;
      const float* xr = x + (size_t)n * DDIM;
      double acc[NEXP];
#pragma unroll
      for (int e = 0; e < NEXP; e++) acc[e] = 0.0;
      for (int i = 0; i < DDIM / 64; i++) {
        int d = i * 64 + lane;
        float xv = xr[d];
        const float* wr = Wg + (size_t)d * NEXP;
#pragma unroll
        for (int e = 0; e < NEXP; e++) acc[e] += (double)xv * (double)wr[e];
      }
#pragma unroll
      for (int e = 0; e < NEXP; e++) {
        double v = acc[e];
#pragma unroll
        for (int off = 32; off; off >>= 1) v += __shfl_xor(v, off);
        acc[e] = v;
      }
      if (lane == 0) {
        int i1 = -1, i2 = -1;
        double s1 = -1e300, s2 = -1e300;
#pragma unroll
        for (int e = 0; e < NEXP; e++) {
          double v = acc[e];
          if (v > s1) { s2 = s1; i2 = i1; s1 = v; i1 = e; }
          else if (v > s2) { s2 = v; i2 = e; }
        }
        float g1 = 1.0f / (1.0f + expf((float)(-s1)));
        float g2 = 1.0f / (1.0f + expf((float)(-s2)));
        int p1 = atomicAdd(&cnts[i1], 1);
        tokL[i1 * CAP + p1] = n;
        int p2 = atomicAdd(&cnts[i2], 1);
        tokL[i2 * CAP + p2] = n;
        pairE[2 * n] = i1; pairS[2 * n] = p1; pairG[2 * n] = g1;
        pairE[2 * n + 1] = i2; pairS[2 * n + 1] = p2; pairG[2 * n + 1] = g2;
      }
    }
  }
}

// offsets + flat m-block table (serial, trivial size)
__global__ void offs_kernel(const int* __restrict__ cnts, int* __restrict__ offs,
                            int* __restrict__ blkE, int* __restrict__ blkS) {
  if (threadIdx.x == 0) {
    int s = 0, nb = 0;
    for (int e = 0; e < NEXP; e++) {
      offs[e] = s;
      for (int st = 0; st < cnts[e]; st += 128) { blkE[nb] = e; blkS[nb] = st; nb++; }
      s += cnts[e];
    }
    offs[NEXP] = s;
    for (; nb < MAXB; nb++) { blkE[nb] = NEXP; blkS[nb] = 0; }
  }
}

// ---------------------------------------------------------------- GEMM1
// H[offs[e]+r, :] = gelu( x[tok[e][r], :] @ W1[e] + b1[e] ), bf16
// XCD swizzle (T1, n-major): wt1 (64 MB) is the dominant stream; xbf (8.4 MB)
// is L3-resident. Each XCD owns a contiguous bx range for ALL m-blocks, so
// each B panel is fetched by exactly one XCD's L2. nwg=2304 %8==0 -> bijective.
__global__ __launch_bounds__(256) void gemm1_kernel(
    const bf16_t* __restrict__ xbf, const bf16_t* __restrict__ wt1,
    const float* __restrict__ b1, const int* __restrict__ tokL,
    const int* __restrict__ cnts, const int* __restrict__ offs,
    const int* __restrict__ blkE, const int* __restrict__ blkS,
    bf16_t* __restrict__ H) {
  const int bid = blockIdx.x + 32 * blockIdx.y;
  const int swz = (bid & 7) * 288 + (bid >> 3);
  const int by = swz % 72;        // m-block (fast within an XCD chunk)
  const int bx = swz / 72;        // n-block (4 per XCD)
  const int e = blkE[by];
  if (e >= NEXP) return;
  const int m0 = blkS[by];
  const int cnt = cnts[e];
  const int n0 = bx * 128;
  const int t = threadIdx.x;

  __shared__ alignas(16) bf16_t As[128 * 32];
  __shared__ alignas(16) bf16_t Bs[128 * 32];

  const int sr = t >> 2;
  const int sc = (t & 3) * 8;
  const int r0 = m0 + sr, r1 = m0 + sr + 64;
  const int tok0 = (r0 < cnt) ? tokL[e * CAP + r0] : 0;
  const int tok1 = (r1 < cnt) ? tokL[e * CAP + r1] : 0;
  const bf16_t* gA0 = xbf + (size_t)tok0 * DDIM + sc;
  const bf16_t* gA1 = xbf + (size_t)tok1 * DDIM + sc;
  const bf16_t* wte = wt1 + (size_t)e * FDIM * DDIM;
  const bf16_t* gB0 = wte + (size_t)(n0 + sr) * DDIM + sc;
  const bf16_t* gB1 = wte + (size_t)(n0 + sr + 64) * DDIM + sc;
  bf16_t* lA0 = As + t * 8; bf16_t* lA1 = As + 2048 + t * 8;
  bf16_t* lB0 = Bs + t * 8; bf16_t* lB1 = Bs + 2048 + t * 8;

  const int lane = t & 63, w = t >> 6;
  const int wm = (w >> 1) * 64, wn = (w & 1) * 64;
  const int lid = lane & 15, quad = lane >> 4;

  f32x4 acc[4][4] = {};
  for (int kk = 0; kk < DDIM; kk += 32) {
    GLOAD_LDS16(gA0 + kk, lA0);
    GLOAD_LDS16(gA1 + kk, lA1);
    GLOAD_LDS16(gB0 + kk, lB0);
    GLOAD_LDS16(gB1 + kk, lB1);
    __syncthreads();
    bf16x8 af[4], bfm[4];
#pragma unroll
    for (int i = 0; i < 4; i++)
      af[i] = *(const bf16x8*)(As + (wm + i * 16 + lid) * 32 + quad * 8);
#pragma unroll
    for (int j = 0; j < 4; j++)
      bfm[j] = *(const bf16x8*)(Bs + (wn + j * 16 + lid) * 32 + quad * 8);
#pragma unroll
    for (int i = 0; i < 4; i++)
#pragma unroll
      for (int j = 0; j < 4; j++)
        acc[i][j] = __builtin_amdgcn_mfma_f32_16x16x32_bf16(af[i], bfm[j], acc[i][j], 0, 0, 0);
    __syncthreads();
  }

  const float* b1e = b1 + (size_t)e * FDIM;
  const int offe = offs[e];
#pragma unroll
  for (int i = 0; i < 4; i++) {
#pragma unroll
    for (int reg = 0; reg < 4; reg++) {
      int pos = m0 + wm + i * 16 + quad * 4 + reg;
      if (pos >= cnt) continue;  // never write pad rows
      size_t hrow = (size_t)(offe + pos);
#pragma unroll
      for (int j = 0; j < 4; j++) {
        int col = n0 + wn + j * 16 + lid;
        float v = acc[i][j][reg] + b1e[col];
        H[hrow * FDIM + col] = (bf16_t)fast_gelu(v);
      }
    }
  }
}

// ---------------------------------------------------------------- GEMM2
// Y[offs[e]+r, :] = H[row, :] @ W2[e]   (single-pass K=4096, no split-K)
// XCD swizzle (T1, m-major): each XCD owns 9 consecutive m-blocks x all 8 n,
// so H panels (A) stay hot in one XCD's L2. nwg=576 %8==0 -> bijective.
__global__ __launch_bounds__(256) void gemm2_kernel(
    const bf16_t* __restrict__ H, const bf16_t* __restrict__ wt2,
    const int* __restrict__ cnts, const int* __restrict__ offs,
    const int* __restrict__ blkE, const int* __restrict__ blkS,
    float* __restrict__ Y) {
  const int bid = blockIdx.x + 8 * blockIdx.y;
  const int swz = (bid & 7) * 72 + (bid >> 3);
  const int bx = swz & 7;         // n-block (fast within an XCD chunk)
  const int by = swz >> 3;        // m-block (9 per XCD)
  const int e = blkE[by];
  if (e >= NEXP) return;
  const int m0 = blkS[by];
  const int cnt = cnts[e];
  const int n0 = bx * 128;
  const int t = threadIdx.x;
  const int offe = offs[e];

  __shared__ alignas(16) bf16_t As[128 * 32];
  __shared__ alignas(16) bf16_t Bs[128 * 32];

  const int sr = t >> 2;
  const int sc = (t & 3) * 8;
  const bf16_t* gA0 = H + (size_t)(offe + m0 + sr) * FDIM + sc;
  const bf16_t* gA1 = H + (size_t)(offe + m0 + sr + 64) * FDIM + sc;
  const bf16_t* wte = wt2 + (size_t)e * DDIM * FDIM;
  const bf16_t* gB0 = wte + (size_t)(n0 + sr) * FDIM + sc;
  const bf16_t* gB1 = wte + (size_t)(n0 + sr + 64) * FDIM + sc;
  bf16_t* lA0 = As + t * 8; bf16_t* lA1 = As + 2048 + t * 8;
  bf16_t* lB0 = Bs + t * 8; bf16_t* lB1 = Bs + 2048 + t * 8;

  const int lane = t & 63, w = t >> 6;
  const int wm = (w >> 1) * 64, wn = (w & 1) * 64;
  const int lid = lane & 15, quad = lane >> 4;

  f32x4 acc[4][4] = {};
  for (int kk = 0; kk < FDIM; kk += 32) {
    GLOAD_LDS16(gA0 + kk, lA0);
    GLOAD_LDS16(gA1 + kk, lA1);
    GLOAD_LDS16(gB0 + kk, lB0);
    GLOAD_LDS16(gB1 + kk, lB1);
    __syncthreads();
    bf16x8 af[4], bfm[4];
#pragma unroll
    for (int i = 0; i < 4; i++)
      af[i] = *(const bf16x8*)(As + (wm + i * 16 + lid) * 32 + quad * 8);
#pragma unroll
    for (int j = 0; j < 4; j++)
      bfm[j] = *(const bf16x8*)(Bs + (wn + j * 16 + lid) * 32 + quad * 8);
#pragma unroll
    for (int i = 0; i < 4; i++)
#pragma unroll
      for (int j = 0; j < 4; j++)
        acc[i][j] = __builtin_amdgcn_mfma_f32_16x16x32_bf16(af[i], bfm[j], acc[i][j], 0, 0, 0);
    __syncthreads();
  }

#pragma unroll
  for (int i = 0; i < 4; i++) {
#pragma unroll
    for (int reg = 0; reg < 4; reg++) {
      int pos = m0 + wm + i * 16 + quad * 4 + reg;
      if (pos >= cnt) continue;
      float* yrow = Y + (size_t)(offe + pos) * DDIM;
#pragma unroll
      for (int j = 0; j < 4; j++) {
        int col = n0 + wn + j * 16 + lid;
        yrow[col] = acc[i][j][reg];
      }
    }
  }
}

// ---------------------------------------------------------------- combine
__global__ __launch_bounds__(256) void combine_kernel(
    const float* __restrict__ Y, const float* __restrict__ b2,
    const int* __restrict__ pairE, const int* __restrict__ pairS,
    const float* __restrict__ pairG, const int* __restrict__ offs,
    float4* __restrict__ out4) {
  const int n = blockIdx.x;
  const int e1 = pairE[2 * n], e2 = pairE[2 * n + 1];
  const int r1 = offs[e1] + pairS[2 * n];
  const int r2 = offs[e2] + pairS[2 * n + 1];
  const float g1 = pairG[2 * n], g2 = pairG[2 * n + 1];
  const int t = threadIdx.x;
  const float4* ya = (const float4*)(Y + (size_t)r1 * DDIM);
  const float4* yb = (const float4*)(Y + (size_t)r2 * DDIM);
  const float4* ba = (const float4*)(b2 + (size_t)e1 * DDIM);
  const float4* bb = (const float4*)(b2 + (size_t)e2 * DDIM);
  float4 a0 = ya[t], c0 = yb[t];
  float4 pa = ba[t], pb = bb[t];
  float4 o;
  o.x = g1 * (a0.x + pa.x) + g2 * (c0.x + pb.x);
  o.y = g1 * (a0.y + pa.y) + g2 * (c0.y + pb.y);
  o.z = g1 * (a0.z + pa.z) + g2 * (c0.z + pb.z);
  o.w = g1 * (a0.w + pa.w) + g2 * (c0.w + pb.w);
  out4[(size_t)n * (DDIM / 4) + t] = o;
}

// ---------------------------------------------------------------- launch
extern "C" void kernel_launch(void* const* d_in, const int* in_sizes, int n_in,
                              void* d_out, int out_size, void* d_ws, size_t ws_size,
                              hipStream_t stream) {
  const float* x  = (const float*)d_in[0];
  const float* Wg = (const float*)d_in[1];
  const float* W1 = (const float*)d_in[2];
  const float* b1 = (const float*)d_in[3];
  const float* W2 = (const float*)d_in[4];
  const float* b2 = (const float*)d_in[5];
  float* out = (float*)d_out;

  char* ws = (char*)d_ws;
  size_t off = 0;
  auto alloc = [&](size_t bytes) -> void* {
    void* p = (void*)(ws + off);
    off += (bytes + 255) & ~(size_t)255;
    return p;
  };
  bf16_t* xbf   = (bf16_t*)alloc((size_t)NTOK * DDIM * 2);
  bf16_t* wt1   = (bf16_t*)alloc((size_t)NEXP * FDIM * DDIM * 2);  // dead after gemm1
  bf16_t* wt2   = (bf16_t*)alloc((size_t)NEXP * DDIM * FDIM * 2);
  bf16_t* H     = (bf16_t*)alloc((size_t)HROWS * FDIM * 2);
  int*    tokL  = (int*)alloc((size_t)NEXP * CAP * 4);
  int*    pairE = (int*)alloc((size_t)NPAIR * 4);
  int*    pairS = (int*)alloc((size_t)NPAIR * 4);
  float*  pairG = (float*)alloc((size_t)NPAIR * 4);
  int*    cnts  = (int*)alloc(64);
  int*    offs  = (int*)alloc(64);
  int*    blkE  = (int*)alloc(MAXB * 4);
  int*    blkS  = (int*)alloc(MAXB * 4);
  if (off > ws_size) return;

  // Y aliases wt1 (64 MiB): wt1 consumed by gemm1 before gemm2 (same stream).
  float* Y = (float*)wt1;

  hipMemsetAsync(cnts, 0, 64, stream);
  prep_kernel<<<PREP_BLOCKS, 256, 0, stream>>>(W1, W2, x, Wg, wt1, wt2, xbf, tokL,
                                               cnts, pairE, pairS, pairG);
  offs_kernel<<<1, 64, 0, stream>>>(cnts, offs, blkE, blkS);
  gemm1_kernel<<<dim3(FDIM / 128, MAXB), 256, 0, stream>>>(
      xbf, wt1, b1, tokL, cnts, offs, blkE, blkS, H);
  gemm2_kernel<<<dim3(DDIM / 128, MAXB), 256, 0, stream>>>(
      H, wt2, cnts, offs, blkE, blkS, Y);
  combine_kernel<<<NTOK, 256, 0, stream>>>(Y, b2, pairE, pairS, pairG, offs,
                                           (float4*)out);
}

// Round 4
// 629.809 us; speedup vs baseline: 1.0889x; 1.0889x over previous
//
#include <hip/hip_runtime.h>
#include <math.h>

typedef __bf16 bf16_t;
typedef __attribute__((ext_vector_type(8))) __bf16 bf16x8;
typedef __attribute__((ext_vector_type(4))) __bf16 bf16x4;
typedef __attribute__((ext_vector_type(4))) float f32x4;

#define NTOK 4096   // B*L tokens
#define DDIM 1024
#define FDIM 4096
#define NEXP 8
#define CAP  4096   // per-expert token capacity (worst case)
#define HROWS (2*NTOK + 128)  // pair count + slack for gemm2 A-tile overreads
#define NPAIR (2*NTOK)
#define MAXB 72     // max live m-blocks: floor(8192/128)+7 = 71

#define PREP_BLOCKS 2048   // 8 blocks/CU: whole grid co-resident, zero churn
#define PREP_UNITS 13312   // [0,4096) W1-T | [4096,8192) W2-T | [8192,12288) x->bf16 | [12288,13312) router

// async 16B global->LDS. LDS dest must be wave-uniform base + lane*16.
#define GLOAD_LDS16(g, l) \
  __builtin_amdgcn_global_load_lds((__attribute__((address_space(1))) void*)(g), \
                                   (__attribute__((address_space(3))) void*)(l), 16, 0, 0)

__device__ __forceinline__ float fast_gelu(float v) {
  float u = 0.7978845608028654f * (v + 0.044715f * v * v * v);
  float uc = fminf(fmaxf(u, -10.f), 10.f);
  float t = __builtin_amdgcn_exp2f(2.885390081777927f * uc);  // e^{2u}
  float th = (t - 1.f) * __builtin_amdgcn_rcpf(t + 1.f);
  return 0.5f * v * (1.0f + th);
}

// ---------------------------------------------------------------- prep
// Persistent grid-stride kernel. 2048 blocks loop over 13312 units so the next
// unit's load burst issues right after the current unit's stores — continuous
// VMEM occupancy (one-shot blocks measured latency-bound at 1.44 TB/s).
__device__ __forceinline__ void reg_transpose(const float* __restrict__ ip,
                                              bf16_t* __restrict__ op,
                                              int R, int C, int r0, int c0,
                                              int t) {
  const int w = t >> 6;
  const int lane = t & 63;
  const int g = lane >> 4;
  const int m = lane & 15;
  const int rr = r0 + w * 32 + 8 * g;   // 8 input rows [rr, rr+8)
  const int cc = c0 + 4 * m;            // 4 input cols [cc, cc+4)
  f32x4 v[8];
#pragma unroll
  for (int ri = 0; ri < 8; ri++)
    v[ri] = *(const f32x4*)(ip + (size_t)(rr + ri) * C + cc);
#pragma unroll
  for (int ci = 0; ci < 4; ci++) {
    bf16x8 o;
#pragma unroll
    for (int ri = 0; ri < 8; ri++) o[ri] = (bf16_t)v[ri][ci];
    *(bf16x8*)(op + (size_t)(cc + ci) * R + rr) = o;
  }
}

__global__ __launch_bounds__(256) void prep_kernel(
    const float* __restrict__ W1, const float* __restrict__ W2,
    const float* __restrict__ x, const float* __restrict__ Wg,
    bf16_t* __restrict__ wt1, bf16_t* __restrict__ wt2,
    bf16_t* __restrict__ xbf, int* __restrict__ tokL, int* __restrict__ cnts,
    int* __restrict__ pairE, int* __restrict__ pairS, float* __restrict__ pairG) {
  const int t = threadIdx.x;
  for (int u = blockIdx.x; u < PREP_UNITS; u += PREP_BLOCKS) {
    if (u < 4096) {  // W1 (E,1024,4096) -> wt1 (E,4096,1024)
      int e = u >> 9, ti = u & 511;
      int r0 = (ti & 7) * 128, c0 = (ti >> 3) * 64;
      reg_transpose(W1 + (size_t)e * DDIM * FDIM, wt1 + (size_t)e * DDIM * FDIM,
                    DDIM, FDIM, r0, c0, t);
    } else if (u < 8192) {  // W2 (E,4096,1024) -> wt2 (E,1024,4096)
      int b0 = u - 4096;
      int e = b0 >> 9, ti = b0 & 511;
      int r0 = (ti & 31) * 128, c0 = (ti >> 5) * 64;
      reg_transpose(W2 + (size_t)e * FDIM * DDIM, wt2 + (size_t)e * FDIM * DDIM,
                    FDIM, DDIM, r0, c0, t);
    } else if (u < 12288) {  // x -> bf16 (exactly covers NTOK*DDIM/4 elements)
      int i = (u - 8192) * 256 + t;
      float4 v = ((const float4*)x)[i];
      bf16x4 o;
      o.x = (bf16_t)v.x; o.y = (bf16_t)v.y; o.z = (bf16_t)v.z; o.w = (bf16_t)v.w;
      ((bf16x4*)xbf)[i] = o;
    } else {  // router: 4 tokens/unit, one wave/token, fp64 logits
      int b0 = u - 12288;
      int wid = t >> 6, lane = t & 63;
      int n = b0 * 4 + wid;
      const float* xr = x + (size_t)n * DDIM;
      double acc[NEXP];
#pragma unroll
      for (int e = 0; e < NEXP; e++) acc[e] = 0.0;
      for (int i = 0; i < DDIM / 64; i++) {
        int d = i * 64 + lane;
        float xv = xr[d];
        const float* wr = Wg + (size_t)d * NEXP;
#pragma unroll
        for (int e = 0; e < NEXP; e++) acc[e] += (double)xv * (double)wr[e];
      }
#pragma unroll
      for (int e = 0; e < NEXP; e++) {
        double v = acc[e];
#pragma unroll
        for (int off = 32; off; off >>= 1) v += __shfl_xor(v, off);
        acc[e] = v;
      }
      if (lane == 0) {
        int i1 = -1, i2 = -1;
        double s1 = -1e300, s2 = -1e300;
#pragma unroll
        for (int e = 0; e < NEXP; e++) {
          double v = acc[e];
          if (v > s1) { s2 = s1; i2 = i1; s1 = v; i1 = e; }
          else if (v > s2) { s2 = v; i2 = e; }
        }
        float g1 = 1.0f / (1.0f + expf((float)(-s1)));
        float g2 = 1.0f / (1.0f + expf((float)(-s2)));
        int p1 = atomicAdd(&cnts[i1], 1);
        tokL[i1 * CAP + p1] = n;
        int p2 = atomicAdd(&cnts[i2], 1);
        tokL[i2 * CAP + p2] = n;
        pairE[2 * n] = i1; pairS[2 * n] = p1; pairG[2 * n] = g1;
        pairE[2 * n + 1] = i2; pairS[2 * n + 1] = p2; pairG[2 * n + 1] = g2;
      }
    }
  }
}

// offsets + flat m-block table (serial, trivial size)
__global__ void offs_kernel(const int* __restrict__ cnts, int* __restrict__ offs,
                            int* __restrict__ blkE, int* __restrict__ blkS) {
  if (threadIdx.x == 0) {
    int s = 0, nb = 0;
    for (int e = 0; e < NEXP; e++) {
      offs[e] = s;
      for (int st = 0; st < cnts[e]; st += 128) { blkE[nb] = e; blkS[nb] = st; nb++; }
      s += cnts[e];
    }
    offs[NEXP] = s;
    for (; nb < MAXB; nb++) { blkE[nb] = NEXP; blkS[nb] = 0; }
  }
}

// ---------------------------------------------------------------- GEMM1
// H[offs[e]+r, :] = gelu( x[tok[e][r], :] @ W1[e] + b1[e] ), bf16
// 2-phase double-buffered LDS (T3-minimum): prefetch tile k+1 before computing
// tile k; single barrier/iter (compiler emits vmcnt(0) lgkmcnt(0) before
// s_barrier, so the prefetch drains AFTER the MFMAs — latency hidden).
// XCD swizzle (T1, n-major): each XCD owns a contiguous bx range.
__global__ __launch_bounds__(256) void gemm1_kernel(
    const bf16_t* __restrict__ xbf, const bf16_t* __restrict__ wt1,
    const float* __restrict__ b1, const int* __restrict__ tokL,
    const int* __restrict__ cnts, const int* __restrict__ offs,
    const int* __restrict__ blkE, const int* __restrict__ blkS,
    bf16_t* __restrict__ H) {
  const int bid = blockIdx.x + 32 * blockIdx.y;
  const int swz = (bid & 7) * 288 + (bid >> 3);
  const int by = swz % 72;        // m-block (fast within an XCD chunk)
  const int bx = swz / 72;        // n-block (4 per XCD)
  const int e = blkE[by];
  if (e >= NEXP) return;
  const int m0 = blkS[by];
  const int cnt = cnts[e];
  const int n0 = bx * 128;
  const int t = threadIdx.x;

  __shared__ alignas(16) bf16_t As[2][128 * 32];
  __shared__ alignas(16) bf16_t Bs[2][128 * 32];

  const int sr = t >> 2;
  const int sc = (t & 3) * 8;
  const int r0 = m0 + sr, r1 = m0 + sr + 64;
  const int tok0 = (r0 < cnt) ? tokL[e * CAP + r0] : 0;
  const int tok1 = (r1 < cnt) ? tokL[e * CAP + r1] : 0;
  const bf16_t* gA0 = xbf + (size_t)tok0 * DDIM + sc;
  const bf16_t* gA1 = xbf + (size_t)tok1 * DDIM + sc;
  const bf16_t* wte = wt1 + (size_t)e * FDIM * DDIM;
  const bf16_t* gB0 = wte + (size_t)(n0 + sr) * DDIM + sc;
  const bf16_t* gB1 = wte + (size_t)(n0 + sr + 64) * DDIM + sc;

  const int lane = t & 63, w = t >> 6;
  const int wm = (w >> 1) * 64, wn = (w & 1) * 64;
  const int lid = lane & 15, quad = lane >> 4;

#define STAGE_G1(buf, kk) do { \
    GLOAD_LDS16(gA0 + (kk), &As[buf][t * 8]); \
    GLOAD_LDS16(gA1 + (kk), &As[buf][2048 + t * 8]); \
    GLOAD_LDS16(gB0 + (kk), &Bs[buf][t * 8]); \
    GLOAD_LDS16(gB1 + (kk), &Bs[buf][2048 + t * 8]); \
  } while (0)

  f32x4 acc[4][4] = {};
  STAGE_G1(0, 0);
  __syncthreads();
  int cur = 0;
  for (int kk = 0; kk < DDIM; kk += 32) {
    if (kk + 32 < DDIM) STAGE_G1(cur ^ 1, kk + 32);
    const bf16_t* Ac = As[cur];
    const bf16_t* Bc = Bs[cur];
    bf16x8 af[4], bfm[4];
#pragma unroll
    for (int i = 0; i < 4; i++)
      af[i] = *(const bf16x8*)(Ac + (wm + i * 16 + lid) * 32 + quad * 8);
#pragma unroll
    for (int j = 0; j < 4; j++)
      bfm[j] = *(const bf16x8*)(Bc + (wn + j * 16 + lid) * 32 + quad * 8);
#pragma unroll
    for (int i = 0; i < 4; i++)
#pragma unroll
      for (int j = 0; j < 4; j++)
        acc[i][j] = __builtin_amdgcn_mfma_f32_16x16x32_bf16(af[i], bfm[j], acc[i][j], 0, 0, 0);
    __syncthreads();  // drains prefetch (vmcnt 0) + ds_reads (lgkm 0)
    cur ^= 1;
  }
#undef STAGE_G1

  const float* b1e = b1 + (size_t)e * FDIM;
  const int offe = offs[e];
#pragma unroll
  for (int i = 0; i < 4; i++) {
#pragma unroll
    for (int reg = 0; reg < 4; reg++) {
      int pos = m0 + wm + i * 16 + quad * 4 + reg;
      if (pos >= cnt) continue;  // never write pad rows
      size_t hrow = (size_t)(offe + pos);
#pragma unroll
      for (int j = 0; j < 4; j++) {
        int col = n0 + wn + j * 16 + lid;
        float v = acc[i][j][reg] + b1e[col];
        H[hrow * FDIM + col] = (bf16_t)fast_gelu(v);
      }
    }
  }
}

// ---------------------------------------------------------------- GEMM2
// Y{0,1}[offs[e]+r, :] = H[row, k-half] @ W2[e][k-half]  (split-K=2 restored
// for concurrency: 1152 blocks ≈ 4.5/CU; splits read DISJOINT H/wt2 halves so
// fetch stays at the swizzled round-3 level). 2-phase double-buffered LDS.
// XCD swizzle: chunk of 144 per XCD = 9 m × 2 split × 8 n, n fastest so the
// 8 same-(m,split) blocks share one A half-panel in their XCD's L2.
__global__ __launch_bounds__(256) void gemm2_kernel(
    const bf16_t* __restrict__ H, const bf16_t* __restrict__ wt2,
    const int* __restrict__ cnts, const int* __restrict__ offs,
    const int* __restrict__ blkE, const int* __restrict__ blkS,
    float* __restrict__ Y0, float* __restrict__ Y1) {
  const int bid = blockIdx.x + 8 * blockIdx.y;      // grid (8, 144)
  const int swz = (bid & 7) * 144 + (bid >> 3);     // nwg=1152 %8==0: bijective
  const int bx = swz & 7;          // n-block (fastest)
  const int split = (swz >> 3) & 1;
  const int by = swz >> 4;         // m-block (9 per XCD)
  const int e = blkE[by];
  if (e >= NEXP) return;
  const int m0 = blkS[by];
  const int cnt = cnts[e];
  const int n0 = bx * 128;
  const int t = threadIdx.x;
  const int offe = offs[e];
  const int k0 = split * (FDIM / 2);

  __shared__ alignas(16) bf16_t As[2][128 * 32];
  __shared__ alignas(16) bf16_t Bs[2][128 * 32];

  const int sr = t >> 2;
  const int sc = (t & 3) * 8;
  const bf16_t* gA0 = H + (size_t)(offe + m0 + sr) * FDIM + sc + k0;
  const bf16_t* gA1 = H + (size_t)(offe + m0 + sr + 64) * FDIM + sc + k0;
  const bf16_t* wte = wt2 + (size_t)e * DDIM * FDIM;
  const bf16_t* gB0 = wte + (size_t)(n0 + sr) * FDIM + sc + k0;
  const bf16_t* gB1 = wte + (size_t)(n0 + sr + 64) * FDIM + sc + k0;

  const int lane = t & 63, w = t >> 6;
  const int wm = (w >> 1) * 64, wn = (w & 1) * 64;
  const int lid = lane & 15, quad = lane >> 4;

#define STAGE_G2(buf, kk) do { \
    GLOAD_LDS16(gA0 + (kk), &As[buf][t * 8]); \
    GLOAD_LDS16(gA1 + (kk), &As[buf][2048 + t * 8]); \
    GLOAD_LDS16(gB0 + (kk), &Bs[buf][t * 8]); \
    GLOAD_LDS16(gB1 + (kk), &Bs[buf][2048 + t * 8]); \
  } while (0)

  f32x4 acc[4][4] = {};
  STAGE_G2(0, 0);
  __syncthreads();
  int cur = 0;
  for (int kk = 0; kk < FDIM / 2; kk += 32) {
    if (kk + 32 < FDIM / 2) STAGE_G2(cur ^ 1, kk + 32);
    const bf16_t* Ac = As[cur];
    const bf16_t* Bc = Bs[cur];
    bf16x8 af[4], bfm[4];
#pragma unroll
    for (int i = 0; i < 4; i++)
      af[i] = *(const bf16x8*)(Ac + (wm + i * 16 + lid) * 32 + quad * 8);
#pragma unroll
    for (int j = 0; j < 4; j++)
      bfm[j] = *(const bf16x8*)(Bc + (wn + j * 16 + lid) * 32 + quad * 8);
#pragma unroll
    for (int i = 0; i < 4; i++)
#pragma unroll
      for (int j = 0; j < 4; j++)
        acc[i][j] = __builtin_amdgcn_mfma_f32_16x16x32_bf16(af[i], bfm[j], acc[i][j], 0, 0, 0);
    __syncthreads();
    cur ^= 1;
  }
#undef STAGE_G2

  float* Ye = split ? Y1 : Y0;
#pragma unroll
  for (int i = 0; i < 4; i++) {
#pragma unroll
    for (int reg = 0; reg < 4; reg++) {
      int pos = m0 + wm + i * 16 + quad * 4 + reg;
      if (pos >= cnt) continue;
      float* yrow = Ye + (size_t)(offe + pos) * DDIM;
#pragma unroll
      for (int j = 0; j < 4; j++) {
        int col = n0 + wn + j * 16 + lid;
        yrow[col] = acc[i][j][reg];
      }
    }
  }
}

// ---------------------------------------------------------------- combine
__global__ __launch_bounds__(256) void combine_kernel(
    const float* __restrict__ Y0, const float* __restrict__ Y1,
    const float* __restrict__ b2, const int* __restrict__ pairE,
    const int* __restrict__ pairS, const float* __restrict__ pairG,
    const int* __restrict__ offs, float4* __restrict__ out4) {
  const int n = blockIdx.x;
  const int e1 = pairE[2 * n], e2 = pairE[2 * n + 1];
  const int r1 = offs[e1] + pairS[2 * n];
  const int r2 = offs[e2] + pairS[2 * n + 1];
  const float g1 = pairG[2 * n], g2 = pairG[2 * n + 1];
  const int t = threadIdx.x;
  const float4* ya0 = (const float4*)(Y0 + (size_t)r1 * DDIM);
  const float4* ya1 = (const float4*)(Y1 + (size_t)r1 * DDIM);
  const float4* yb0 = (const float4*)(Y0 + (size_t)r2 * DDIM);
  const float4* yb1 = (const float4*)(Y1 + (size_t)r2 * DDIM);
  const float4* ba = (const float4*)(b2 + (size_t)e1 * DDIM);
  const float4* bb = (const float4*)(b2 + (size_t)e2 * DDIM);
  float4 a0 = ya0[t], a1 = ya1[t], c0 = yb0[t], c1 = yb1[t];
  float4 pa = ba[t], pb = bb[t];
  float4 o;
  o.x = g1 * (a0.x + a1.x + pa.x) + g2 * (c0.x + c1.x + pb.x);
  o.y = g1 * (a0.y + a1.y + pa.y) + g2 * (c0.y + c1.y + pb.y);
  o.z = g1 * (a0.z + a1.z + pa.z) + g2 * (c0.z + c1.z + pb.z);
  o.w = g1 * (a0.w + a1.w + pa.w) + g2 * (c0.w + c1.w + pb.w);
  out4[(size_t)n * (DDIM / 4) + t] = o;
}

// ---------------------------------------------------------------- launch
extern "C" void kernel_launch(void* const* d_in, const int* in_sizes, int n_in,
                              void* d_out, int out_size, void* d_ws, size_t ws_size,
                              hipStream_t stream) {
  const float* x  = (const float*)d_in[0];
  const float* Wg = (const float*)d_in[1];
  const float* W1 = (const float*)d_in[2];
  const float* b1 = (const float*)d_in[3];
  const float* W2 = (const float*)d_in[4];
  const float* b2 = (const float*)d_in[5];
  float* out = (float*)d_out;

  char* ws = (char*)d_ws;
  size_t off = 0;
  auto alloc = [&](size_t bytes) -> void* {
    void* p = (void*)(ws + off);
    off += (bytes + 255) & ~(size_t)255;
    return p;
  };
  bf16_t* xbf   = (bf16_t*)alloc((size_t)NTOK * DDIM * 2);
  bf16_t* wt1   = (bf16_t*)alloc((size_t)NEXP * FDIM * DDIM * 2);  // dead after gemm1
  bf16_t* wt2   = (bf16_t*)alloc((size_t)NEXP * DDIM * FDIM * 2);
  bf16_t* H     = (bf16_t*)alloc((size_t)HROWS * FDIM * 2);
  int*    tokL  = (int*)alloc((size_t)NEXP * CAP * 4);
  int*    pairE = (int*)alloc((size_t)NPAIR * 4);
  int*    pairS = (int*)alloc((size_t)NPAIR * 4);
  float*  pairG = (float*)alloc((size_t)NPAIR * 4);
  int*    cnts  = (int*)alloc(64);
  int*    offs  = (int*)alloc(64);
  int*    blkE  = (int*)alloc(MAXB * 4);
  int*    blkS  = (int*)alloc(MAXB * 4);
  if (off > ws_size) return;

  // Y0/Y1 alias wt1 (64 MiB): wt1 consumed by gemm1 before gemm2 (same stream).
  float* Y0 = (float*)wt1;
  float* Y1 = Y0 + (size_t)8192 * DDIM;

  hipMemsetAsync(cnts, 0, 64, stream);
  prep_kernel<<<PREP_BLOCKS, 256, 0, stream>>>(W1, W2, x, Wg, wt1, wt2, xbf, tokL,
                                               cnts, pairE, pairS, pairG);
  offs_kernel<<<1, 64, 0, stream>>>(cnts, offs, blkE, blkS);
  gemm1_kernel<<<dim3(FDIM / 128, MAXB), 256, 0, stream>>>(
      xbf, wt1, b1, tokL, cnts, offs, blkE, blkS, H);
  gemm2_kernel<<<dim3(DDIM / 128, MAXB * 2), 256, 0, stream>>>(
      H, wt2, cnts, offs, blkE, blkS, Y0, Y1);
  combine_kernel<<<NTOK, 256, 0, stream>>>(Y0, Y1, b2, pairE, pairS, pairG, offs,
                                           (float4*)out);
}